// Round 5
// baseline (219.028 us; speedup 1.0000x reference)
//
#include <hip/hip_runtime.h>

#define NN 100000
#define NE 1600000
#define HIDN 256
#define OD0 20000
#define OD1 1881
#define OD2 27000
#define OUT_TOTAL (OD0 + OD1 + OD2)

// caps (expected: nL1 ~48, nS1 ~51, nL2 ~820, nS2 ~900)
#define MAXL1 8192
#define MAXS1 112        // LDS-resident cap in k_tail; expected ~51
#define MAXL2 65536
#define MAXS2 8192

#define MASKW 3200       // ceil(100000/32)=3125, padded to int4 multiple

__device__ __forceinline__ float wave_sum64(float v) {
#pragma unroll
    for (int off = 32; off >= 1; off >>= 1) v += __shfl_xor(v, off, 64);
    return v;
}

// set membership bit; on 0->1 transition allocate a slot
__device__ __forceinline__ void insert_set(unsigned* mask, int* cnt, int cap,
                                           int* slot, int* list, int n) {
    unsigned bit = 1u << (n & 31);
    unsigned old = atomicOr(&mask[n >> 5], bit);
    if (!(old & bit)) {
        int s = atomicAdd(cnt, 1);
        if (s < cap) { slot[n] = s; list[s] = n; }
    }
}

// ---- 1: zero the [cnts | mask1 | mask2 | degc] region (contiguous, int4)
__global__ void k_init(int4* base, int n4) {
    int i = blockIdx.x * blockDim.x + threadIdx.x;
    int4 z = make_int4(0, 0, 0, 0);
    for (; i < n4; i += gridDim.x * blockDim.x) base[i] = z;
}

// ---- 2: collect edges with col<3 -> L1; build S1 = {0,1,2} U rows(L1) inline
__global__ __launch_bounds__(256) void k_scan1(
        const int* __restrict__ erow, const int* __restrict__ ecol,
        int* __restrict__ cnts, unsigned* __restrict__ mask1,
        int* __restrict__ slot1, int* __restrict__ S1, int2* __restrict__ L1) {
    int gid = blockIdx.x * blockDim.x + threadIdx.x;
    if (gid < 3) insert_set(mask1, &cnts[1], MAXS1, slot1, S1, gid);
    for (int i = gid; i < NE / 4; i += gridDim.x * blockDim.x) {
        int4 c4 = ((const int4*)ecol)[i];
        int cs[4] = {c4.x, c4.y, c4.z, c4.w};
#pragma unroll
        for (int u = 0; u < 4; u++) {
            if (cs[u] < 3) {
                int r = erow[i * 4 + u];
                int idx = atomicAdd(&cnts[0], 1);
                if (idx < MAXL1) L1[idx] = make_int2(r, cs[u]);
                insert_set(mask1, &cnts[1], MAXS1, slot1, S1, r);
            }
        }
    }
}

// ---- 3: collect edges with col in S1 -> L2; build S2 = rows(L2) U S1 inline
__global__ __launch_bounds__(256) void k_scan2(
        const int* __restrict__ erow, const int* __restrict__ ecol,
        int* __restrict__ cnts, const unsigned* __restrict__ mask1,
        unsigned* __restrict__ mask2, int* __restrict__ slot2,
        int* __restrict__ S2, const int* __restrict__ S1, int2* __restrict__ L2) {
    int gid = blockIdx.x * blockDim.x + threadIdx.x;
    int ns1 = min(cnts[1], MAXS1);
    if (gid < ns1) insert_set(mask2, &cnts[3], MAXS2, slot2, S2, S1[gid]);
    for (int i = gid; i < NE / 4; i += gridDim.x * blockDim.x) {
        int4 c4 = ((const int4*)ecol)[i];
        int cs[4] = {c4.x, c4.y, c4.z, c4.w};
#pragma unroll
        for (int u = 0; u < 4; u++) {
            int c = cs[u];
            if (mask1[c >> 5] & (1u << (c & 31))) {
                int r = erow[i * 4 + u];
                int idx = atomicAdd(&cnts[2], 1);
                if (idx < MAXL2) L2[idx] = make_int2(r, c);
                insert_set(mask2, &cnts[3], MAXS2, slot2, S2, r);
            }
        }
    }
}

// ---- 4: degree scan (S2 members only) + attention/LN0/h1 over S2, fused
#define DX_GRID 256
__global__ __launch_bounds__(256) void k_degx0(
        const int* __restrict__ cnts, const int* __restrict__ ecol,
        const unsigned* __restrict__ mask2, const int* __restrict__ slot2,
        int* __restrict__ degc,
        const int* __restrict__ S2, const float* __restrict__ latent,
        const float* __restrict__ wq, const float* __restrict__ bq,
        const float* __restrict__ wk, const float* __restrict__ bk,
        const float* __restrict__ wv, const float* __restrict__ bv,
        const float* __restrict__ ln0w, const float* __restrict__ ln0b,
        const float* __restrict__ g1w,
        float* __restrict__ x0c, float* __restrict__ h1c) {
    __shared__ float lw[3 * 4096];   // wq | wk | wv staged (48 KB)
    int t = threadIdx.x, b = blockIdx.x;
    int gid = b * 256 + t;
    // stage weights (loads in flight while we do the edge slice)
    {
        const float4* s0 = (const float4*)wq;
        const float4* s1 = (const float4*)wk;
        const float4* s2 = (const float4*)wv;
        float4* d0 = (float4*)&lw[0];
        float4* d1 = (float4*)&lw[4096];
        float4* d2 = (float4*)&lw[8192];
        for (int i = t; i < 1024; i += 256) { d0[i] = s0[i]; d1[i] = s1[i]; d2[i] = s2[i]; }
    }
    // degree slice: count in-edges whose col is in S2
    for (int i = gid; i < NE / 4; i += DX_GRID * 256) {
        int4 c4 = ((const int4*)ecol)[i];
        int cs[4] = {c4.x, c4.y, c4.z, c4.w};
#pragma unroll
        for (int u = 0; u < 4; u++) {
            int c = cs[u];
            if (mask2[c >> 5] & (1u << (c & 31))) {
                int s = slot2[c];
                if ((unsigned)s < MAXS2) atomicAdd(&degc[s], 1);
            }
        }
    }
    __syncthreads();
    int lane = t & 63, wid = t >> 6;
    int nS2 = min(cnts[3], MAXS2);
    for (int s = b * 4 + wid; s < nS2; s += DX_GRID * 4) {
        int n = S2[s];
        float xv = latent[n * 64 + lane];
        float aq = bq[lane], ak = bk[lane], av = bv[lane];
#pragma unroll
        for (int j = 0; j < 64; j++) {
            float xj = __shfl(xv, j, 64);
            aq = fmaf(xj, lw[j * 64 + lane], aq);
            ak = fmaf(xj, lw[4096 + j * 64 + lane], ak);
            av = fmaf(xj, lw[8192 + j * 64 + lane], av);
        }
        // 4-head attention via shfl; lane = h*16+d
        int d = lane & 15;
        float sj[4];
#pragma unroll
        for (int j = 0; j < 4; j++) {
            float kv = __shfl(ak, (j << 4) | d, 64);
            float pp = aq * kv;
            pp += __shfl_xor(pp, 1, 64); pp += __shfl_xor(pp, 2, 64);
            pp += __shfl_xor(pp, 4, 64); pp += __shfl_xor(pp, 8, 64);
            sj[j] = pp * 0.25f;   // / sqrt(16)
        }
        float mx = fmaxf(fmaxf(sj[0], sj[1]), fmaxf(sj[2], sj[3]));
        float e0 = expf(sj[0] - mx), e1 = expf(sj[1] - mx);
        float e2 = expf(sj[2] - mx), e3 = expf(sj[3] - mx);
        float inv = 1.f / (e0 + e1 + e2 + e3);
        float at[4] = {e0 * inv, e1 * inv, e2 * inv, e3 * inv};
        float o = 0.f;
#pragma unroll
        for (int j = 0; j < 4; j++) {
            float vv = __shfl(av, (j << 4) | d, 64);
            o = fmaf(at[j], vv, o);
        }
        float sum = wave_sum64(o), sq = wave_sum64(o * o);
        float mean = sum * (1.f / 64.f);
        float var = sq * (1.f / 64.f) - mean * mean;
        float x0 = (o - mean) * rsqrtf(var + 1e-5f) * ln0w[lane] + ln0b[lane];
        x0c[s * 64 + lane] = x0;
        float h = 0.f;
#pragma unroll
        for (int j = 0; j < 64; j++) {
            float xj = __shfl(x0, j, 64);
            h = fmaf(xj, g1w[j * 64 + lane], h);
        }
        h1c[s * 64 + lane] = h;
    }
}

// ---- 5: single-block tail: agg1 (LDS) -> x1 -> h2 -> agg2 -> x2 -> hg
__global__ __launch_bounds__(256) void k_tail(
        const int* __restrict__ cnts, const int2* __restrict__ L1,
        const int2* __restrict__ L2, const int* __restrict__ S1,
        const int* __restrict__ slot1, const int* __restrict__ slot2,
        const int* __restrict__ degc,
        const float* __restrict__ x0c, const float* __restrict__ h1c,
        const float* __restrict__ g1b, const float* __restrict__ ln1w,
        const float* __restrict__ ln1b, const float* __restrict__ g2w,
        const float* __restrict__ g2b, const float* __restrict__ ln2w,
        const float* __restrict__ ln2b,
        const float* __restrict__ w10, const float* __restrict__ b10,
        const float* __restrict__ w11, const float* __restrict__ b11,
        const float* __restrict__ w12, const float* __restrict__ b12,
        float* __restrict__ hg) {
    __shared__ float s_acc[MAXS1 * 64];   // agg1, then x1 (28 KB)
    __shared__ float s_h2[MAXS1 * 64];    // h2 (28 KB)
    __shared__ float s_agg2[192], s_x2[192];
    int t = threadIdx.x, lane = t & 63, wid = t >> 6;
    int nl1 = min(cnts[0], MAXL1);
    int ns1 = min(cnts[1], MAXS1);
    int nl2 = min(cnts[2], MAXL2);
    for (int i = t; i < MAXS1 * 64; i += 256) s_acc[i] = 0.f;
    if (t < 192) s_agg2[t] = 0.f;
    __syncthreads();
    // agg1 over L2 edges + S1 self-loops
    for (int e = wid; e < nl2 + ns1; e += 4) {
        int r, c;
        if (e < nl2) { int2 rc = L2[e]; r = rc.x; c = rc.y; }
        else { r = c = S1[e - nl2]; }
        int sr2 = slot2[r], sc2 = slot2[c], sc1 = slot1[c];
        if ((unsigned)sr2 >= MAXS2 || (unsigned)sc2 >= MAXS2 || (unsigned)sc1 >= (unsigned)ns1) continue;
        float wgt = rsqrtf((float)(degc[sr2] + 1)) * rsqrtf((float)(degc[sc2] + 1));
        atomicAdd(&s_acc[sc1 * 64 + lane], h1c[sr2 * 64 + lane] * wgt);
    }
    __syncthreads();
    // x1 = LN(x0 + agg1 + g1b); h2 = x1 @ g2w
    for (int s = wid; s < ns1; s += 4) {
        int s2 = slot2[S1[s]];
        float v = x0c[s2 * 64 + lane] + s_acc[s * 64 + lane] + g1b[lane];
        float sum = wave_sum64(v), sq = wave_sum64(v * v);
        float mean = sum * (1.f / 64.f);
        float var = sq * (1.f / 64.f) - mean * mean;
        float x1 = (v - mean) * rsqrtf(var + 1e-5f) * ln1w[lane] + ln1b[lane];
        s_acc[s * 64 + lane] = x1;
        float h = 0.f;
#pragma unroll
        for (int j = 0; j < 64; j++) {
            float xj = __shfl(x1, j, 64);
            h = fmaf(xj, g2w[j * 64 + lane], h);
        }
        s_h2[s * 64 + lane] = h;
    }
    __syncthreads();
    // agg2 over L1 edges + {0,1,2} self-loops
    for (int e = wid; e < nl1 + 3; e += 4) {
        int r, c;
        if (e < nl1) { int2 rc = L1[e]; r = rc.x; c = rc.y; }
        else { r = c = e - nl1; }
        int sr1 = slot1[r], sr2 = slot2[r], sc2 = slot2[c];
        if ((unsigned)sr1 >= (unsigned)ns1 || (unsigned)sr2 >= MAXS2 || (unsigned)sc2 >= MAXS2) continue;
        float wgt = rsqrtf((float)(degc[sr2] + 1)) * rsqrtf((float)(degc[sc2] + 1));
        atomicAdd(&s_agg2[c * 64 + lane], s_h2[sr1 * 64 + lane] * wgt);
    }
    __syncthreads();
    // x2 = LN(x1 + agg2 + g2b), nodes 0..2
    if (wid < 3) {
        int s1 = slot1[wid];
        float v = s_acc[s1 * 64 + lane] + s_agg2[wid * 64 + lane] + g2b[lane];
        float sum = wave_sum64(v), sq = wave_sum64(v * v);
        float mean = sum * (1.f / 64.f);
        float var = sq * (1.f / 64.f) - mean * mean;
        s_x2[wid * 64 + lane] = (v - mean) * rsqrtf(var + 1e-5f) * ln2w[lane] + ln2b[lane];
    }
    __syncthreads();
    // hg = relu(x2 @ gw1 + gb1)
    const float* W1[3] = {w10, w11, w12};
    const float* B1[3] = {b10, b11, b12};
#pragma unroll
    for (int gi = 0; gi < 3; gi++) {
        float acc = B1[gi][t];
#pragma unroll
        for (int j = 0; j < 64; j++) acc = fmaf(s_x2[gi * 64 + j], W1[gi][j * 256 + t], acc);
        hg[gi * 256 + t] = fmaxf(acc, 0.f);
    }
}

// ---- 6: out GEMV, split-K: 4 waves x 64 cols per block
__global__ __launch_bounds__(256) void k_out(const float* __restrict__ hg,
        const float* __restrict__ w20, const float* __restrict__ b20,
        const float* __restrict__ w21, const float* __restrict__ b21,
        const float* __restrict__ w22, const float* __restrict__ b22,
        float* __restrict__ out) {
    __shared__ float lh[768];
    __shared__ float part[256];
    int t = threadIdx.x;
    lh[t] = hg[t]; lh[t + 256] = hg[t + 256]; lh[t + 512] = hg[t + 512];
    __syncthreads();
    int tx = t & 63, ty = t >> 6;
    int o = blockIdx.x * 64 + tx;
    int gi = -1, jj = 0, od = 1;
    const float* w2 = w20;
    if (o < OD0)                 { gi = 0; jj = o;             od = OD0; w2 = w20; }
    else if (o < OD0 + OD1)      { gi = 1; jj = o - OD0;       od = OD1; w2 = w21; }
    else if (o < OUT_TOTAL)      { gi = 2; jj = o - OD0 - OD1; od = OD2; w2 = w22; }
    float acc = 0.f;
    if (gi >= 0) {
        const float* h = &lh[gi * 256 + ty * 64];
        const float* wp = &w2[(size_t)(ty * 64) * od + jj];
#pragma unroll 16
        for (int k = 0; k < 64; k++) acc = fmaf(h[k], wp[(size_t)k * od], acc);
    }
    part[t] = acc;
    __syncthreads();
    if (t < 64 && gi >= 0) {
        float r = part[t] + part[t + 64] + part[t + 128] + part[t + 192];
        const float* b2 = (gi == 0) ? b20 : (gi == 1) ? b21 : b22;
        out[o] = r + b2[jj];
    }
}

extern "C" void kernel_launch(void* const* d_in, const int* in_sizes, int n_in,
                              void* d_out, int out_size, void* d_ws, size_t ws_size,
                              hipStream_t stream) {
    (void)in_sizes; (void)n_in; (void)out_size; (void)ws_size;
    const float* latent = (const float*)d_in[0];
    const int*   edges  = (const int*)d_in[1];
    const float* wq  = (const float*)d_in[2];
    const float* bq  = (const float*)d_in[3];
    const float* wk  = (const float*)d_in[4];
    const float* bk  = (const float*)d_in[5];
    const float* wv  = (const float*)d_in[6];
    const float* bv  = (const float*)d_in[7];
    const float* ln0w = (const float*)d_in[8];
    const float* ln0b = (const float*)d_in[9];
    const float* g1w  = (const float*)d_in[10];
    const float* g1b  = (const float*)d_in[11];
    const float* ln1w = (const float*)d_in[12];
    const float* ln1b = (const float*)d_in[13];
    const float* g2w  = (const float*)d_in[14];
    const float* g2b  = (const float*)d_in[15];
    const float* ln2w = (const float*)d_in[16];
    const float* ln2b = (const float*)d_in[17];
    const float* gw1_0 = (const float*)d_in[18];
    const float* gb1_0 = (const float*)d_in[19];
    const float* gw2_0 = (const float*)d_in[20];
    const float* gb2_0 = (const float*)d_in[21];
    const float* gw1_1 = (const float*)d_in[22];
    const float* gb1_1 = (const float*)d_in[23];
    const float* gw2_1 = (const float*)d_in[24];
    const float* gb2_1 = (const float*)d_in[25];
    const float* gw1_2 = (const float*)d_in[26];
    const float* gb1_2 = (const float*)d_in[27];
    const float* gw2_2 = (const float*)d_in[28];
    const float* gb2_2 = (const float*)d_in[29];

    // workspace carve: [cnts|mask1|mask2|degc] contiguous -> zeroed by k_init
    char* ptr = (char*)d_ws;
    auto alloc = [&](size_t bytes) { char* r = ptr; ptr += (bytes + 255) & ~(size_t)255; return r; };
    int*      cnts  = (int*)alloc(64 * 4);        // [0]=nL1 [1]=nS1 [2]=nL2 [3]=nS2
    unsigned* mask1 = (unsigned*)alloc(MASKW * 4);
    unsigned* mask2 = (unsigned*)alloc(MASKW * 4);
    int*      degc  = (int*)alloc((size_t)MAXS2 * 4);
    char*     zero_end = ptr;
    int*      slot1 = (int*)alloc((size_t)NN * 4);   // valid only where mask1 bit set
    int*      slot2 = (int*)alloc((size_t)NN * 4);   // valid only where mask2 bit set
    int2*     L1    = (int2*)alloc((size_t)MAXL1 * 8);
    int*      S1    = (int*)alloc((size_t)MAXS1 * 4);
    int2*     L2    = (int2*)alloc((size_t)MAXL2 * 8);
    int*      S2    = (int*)alloc((size_t)MAXS2 * 4);
    float*    x0c   = (float*)alloc((size_t)MAXS2 * 64 * 4);
    float*    h1c   = (float*)alloc((size_t)MAXS2 * 64 * 4);
    float*    hg    = (float*)alloc(3 * HIDN * 4);

    const int* erow = edges;
    const int* ecol = edges + NE;
    int zero_n4 = (int)((zero_end - (char*)cnts) / 16);

    const int SCAN_GRID = (NE / 4 + 255) / 256;
    k_init<<<16, 256, 0, stream>>>((int4*)cnts, zero_n4);
    k_scan1<<<SCAN_GRID, 256, 0, stream>>>(erow, ecol, cnts, mask1, slot1, S1, L1);
    k_scan2<<<SCAN_GRID, 256, 0, stream>>>(erow, ecol, cnts, mask1, mask2, slot2, S2, S1, L2);
    k_degx0<<<DX_GRID, 256, 0, stream>>>(cnts, ecol, mask2, slot2, degc, S2, latent,
                                         wq, bq, wk, bk, wv, bv, ln0w, ln0b, g1w, x0c, h1c);
    k_tail<<<1, 256, 0, stream>>>(cnts, L1, L2, S1, slot1, slot2, degc, x0c, h1c,
                                  g1b, ln1w, ln1b, g2w, g2b, ln2w, ln2b,
                                  gw1_0, gb1_0, gw1_1, gb1_1, gw1_2, gb1_2, hg);
    k_out<<<(OUT_TOTAL + 63) / 64, 256, 0, stream>>>(hg, gw2_0, gb2_0, gw2_1, gb2_1,
                                                     gw2_2, gb2_2, (float*)d_out);
}

// Round 6
// 203.275 us; speedup vs baseline: 1.0775x; 1.0775x over previous
//
#include <hip/hip_runtime.h>

#define NN 100000
#define NE 1600000
#define HIDN 256
#define OD0 20000
#define OD1 1881
#define OD2 27000
#define OUT_TOTAL (OD0 + OD1 + OD2)

// caps (expected: nL1 ~48, nS1 ~51, nL2 ~820, nS2 ~900)
#define MAXL1 8192
#define MAXS1 112        // LDS-resident cap in k_tail; expected ~51
#define MAXL2 65536
#define MAXS2 8192

#define MASKW 3200       // ceil(100000/32)=3125, padded to int4 multiple
#define CHUNK 256        // edge-resolve chunk in k_tail

__device__ __forceinline__ float wave_sum64(float v) {
#pragma unroll
    for (int off = 32; off >= 1; off >>= 1) v += __shfl_xor(v, off, 64);
    return v;
}

// set membership bit; on 0->1 transition allocate a slot
__device__ __forceinline__ void insert_set(unsigned* mask, int* cnt, int cap,
                                           int* slot, int* list, int n) {
    unsigned bit = 1u << (n & 31);
    unsigned old = atomicOr(&mask[n >> 5], bit);
    if (!(old & bit)) {
        int s = atomicAdd(cnt, 1);
        if (s < cap) { slot[n] = s; list[s] = n; }
    }
}

// ---- 1: zero the [cnts | mask1 | mask2 | degc] region (contiguous, int4)
__global__ void k_init(int4* base, int n4) {
    int i = blockIdx.x * blockDim.x + threadIdx.x;
    int4 z = make_int4(0, 0, 0, 0);
    for (; i < n4; i += gridDim.x * blockDim.x) base[i] = z;
}

// ---- 2: collect edges with col<3 -> L1; build S1 = {0,1,2} U rows(L1) inline
__global__ __launch_bounds__(256) void k_scan1(
        const int* __restrict__ erow, const int* __restrict__ ecol,
        int* __restrict__ cnts, unsigned* __restrict__ mask1,
        int* __restrict__ slot1, int* __restrict__ S1, int2* __restrict__ L1) {
    int gid = blockIdx.x * blockDim.x + threadIdx.x;
    if (gid < 3) insert_set(mask1, &cnts[1], MAXS1, slot1, S1, gid);
    for (int i = gid; i < NE / 4; i += gridDim.x * blockDim.x) {
        int4 c4 = ((const int4*)ecol)[i];
        int cs[4] = {c4.x, c4.y, c4.z, c4.w};
#pragma unroll
        for (int u = 0; u < 4; u++) {
            if (cs[u] < 3) {
                int r = erow[i * 4 + u];
                int idx = atomicAdd(&cnts[0], 1);
                if (idx < MAXL1) L1[idx] = make_int2(r, cs[u]);
                insert_set(mask1, &cnts[1], MAXS1, slot1, S1, r);
            }
        }
    }
}

// ---- 3: collect edges with col in S1 -> L2; build S2 = rows(L2) U S1 inline
__global__ __launch_bounds__(256) void k_scan2(
        const int* __restrict__ erow, const int* __restrict__ ecol,
        int* __restrict__ cnts, const unsigned* __restrict__ mask1,
        unsigned* __restrict__ mask2, int* __restrict__ slot2,
        int* __restrict__ S2, const int* __restrict__ S1, int2* __restrict__ L2) {
    int gid = blockIdx.x * blockDim.x + threadIdx.x;
    int ns1 = min(cnts[1], MAXS1);
    if (gid < ns1) insert_set(mask2, &cnts[3], MAXS2, slot2, S2, S1[gid]);
    for (int i = gid; i < NE / 4; i += gridDim.x * blockDim.x) {
        int4 c4 = ((const int4*)ecol)[i];
        int cs[4] = {c4.x, c4.y, c4.z, c4.w};
#pragma unroll
        for (int u = 0; u < 4; u++) {
            int c = cs[u];
            if (mask1[c >> 5] & (1u << (c & 31))) {
                int r = erow[i * 4 + u];
                int idx = atomicAdd(&cnts[2], 1);
                if (idx < MAXL2) L2[idx] = make_int2(r, c);
                insert_set(mask2, &cnts[3], MAXS2, slot2, S2, r);
            }
        }
    }
}

// ---- 4: degree scan (S2 members only) + attention/LN0/h1 over S2, fused
#define DX_GRID 256
__global__ __launch_bounds__(256) void k_degx0(
        const int* __restrict__ cnts, const int* __restrict__ ecol,
        const unsigned* __restrict__ mask2, const int* __restrict__ slot2,
        int* __restrict__ degc,
        const int* __restrict__ S2, const float* __restrict__ latent,
        const float* __restrict__ wq, const float* __restrict__ bq,
        const float* __restrict__ wk, const float* __restrict__ bk,
        const float* __restrict__ wv, const float* __restrict__ bv,
        const float* __restrict__ ln0w, const float* __restrict__ ln0b,
        const float* __restrict__ g1w,
        float* __restrict__ x0c, float* __restrict__ h1c) {
    __shared__ float lw[3 * 4096];   // wq | wk | wv staged (48 KB)
    int t = threadIdx.x, b = blockIdx.x;
    int gid = b * 256 + t;
    // stage weights (loads in flight while we do the edge slice)
    {
        const float4* s0 = (const float4*)wq;
        const float4* s1 = (const float4*)wk;
        const float4* s2 = (const float4*)wv;
        float4* d0 = (float4*)&lw[0];
        float4* d1 = (float4*)&lw[4096];
        float4* d2 = (float4*)&lw[8192];
        for (int i = t; i < 1024; i += 256) { d0[i] = s0[i]; d1[i] = s1[i]; d2[i] = s2[i]; }
    }
    // degree slice: count in-edges whose col is in S2
    for (int i = gid; i < NE / 4; i += DX_GRID * 256) {
        int4 c4 = ((const int4*)ecol)[i];
        int cs[4] = {c4.x, c4.y, c4.z, c4.w};
#pragma unroll
        for (int u = 0; u < 4; u++) {
            int c = cs[u];
            if (mask2[c >> 5] & (1u << (c & 31))) {
                int s = slot2[c];
                if ((unsigned)s < MAXS2) atomicAdd(&degc[s], 1);
            }
        }
    }
    __syncthreads();
    int lane = t & 63, wid = t >> 6;
    int nS2 = min(cnts[3], MAXS2);
    for (int s = b * 4 + wid; s < nS2; s += DX_GRID * 4) {
        int n = S2[s];
        float xv = latent[n * 64 + lane];
        float aq = bq[lane], ak = bk[lane], av = bv[lane];
#pragma unroll
        for (int j = 0; j < 64; j++) {
            float xj = __shfl(xv, j, 64);
            aq = fmaf(xj, lw[j * 64 + lane], aq);
            ak = fmaf(xj, lw[4096 + j * 64 + lane], ak);
            av = fmaf(xj, lw[8192 + j * 64 + lane], av);
        }
        // 4-head attention via shfl; lane = h*16+d
        int d = lane & 15;
        float sj[4];
#pragma unroll
        for (int j = 0; j < 4; j++) {
            float kv = __shfl(ak, (j << 4) | d, 64);
            float pp = aq * kv;
            pp += __shfl_xor(pp, 1, 64); pp += __shfl_xor(pp, 2, 64);
            pp += __shfl_xor(pp, 4, 64); pp += __shfl_xor(pp, 8, 64);
            sj[j] = pp * 0.25f;   // / sqrt(16)
        }
        float mx = fmaxf(fmaxf(sj[0], sj[1]), fmaxf(sj[2], sj[3]));
        float e0 = expf(sj[0] - mx), e1 = expf(sj[1] - mx);
        float e2 = expf(sj[2] - mx), e3 = expf(sj[3] - mx);
        float inv = 1.f / (e0 + e1 + e2 + e3);
        float at[4] = {e0 * inv, e1 * inv, e2 * inv, e3 * inv};
        float o = 0.f;
#pragma unroll
        for (int j = 0; j < 4; j++) {
            float vv = __shfl(av, (j << 4) | d, 64);
            o = fmaf(at[j], vv, o);
        }
        float sum = wave_sum64(o), sq = wave_sum64(o * o);
        float mean = sum * (1.f / 64.f);
        float var = sq * (1.f / 64.f) - mean * mean;
        float x0 = (o - mean) * rsqrtf(var + 1e-5f) * ln0w[lane] + ln0b[lane];
        x0c[s * 64 + lane] = x0;
        float h = 0.f;
#pragma unroll
        for (int j = 0; j < 64; j++) {
            float xj = __shfl(x0, j, 64);
            h = fmaf(xj, g1w[j * 64 + lane], h);
        }
        h1c[s * 64 + lane] = h;
    }
}

// ---- 5: single-block tail with chunked resolve->accumulate (latency-hiding)
__global__ __launch_bounds__(256) void k_tail(
        const int* __restrict__ cnts, const int2* __restrict__ L1,
        const int2* __restrict__ L2, const int* __restrict__ S1,
        const int* __restrict__ slot1, const int* __restrict__ slot2,
        const int* __restrict__ degc,
        const float* __restrict__ x0c, const float* __restrict__ h1c,
        const float* __restrict__ g1b, const float* __restrict__ ln1w,
        const float* __restrict__ ln1b, const float* __restrict__ g2w,
        const float* __restrict__ g2b, const float* __restrict__ ln2w,
        const float* __restrict__ ln2b,
        const float* __restrict__ w10, const float* __restrict__ b10,
        const float* __restrict__ w11, const float* __restrict__ b11,
        const float* __restrict__ w12, const float* __restrict__ b12,
        float* __restrict__ hg) {
    __shared__ float s_acc[MAXS1 * 64];   // agg1, then x1 (28 KB)
    __shared__ float s_h2[MAXS1 * 64];    // h2 (28 KB)
    __shared__ float s_agg2[192], s_x2[192];
    __shared__ int   e_a[CHUNK];          // resolved src slot
    __shared__ int   e_b[CHUNK];          // resolved dst slot
    __shared__ float e_w[CHUNK];          // resolved weight
    __shared__ int   s_s2i[MAXS1];        // slot2[S1[s]]
    int t = threadIdx.x, lane = t & 63, wid = t >> 6;
    int nl1 = min(cnts[0], MAXL1);
    int ns1 = min(cnts[1], MAXS1);
    int nl2 = min(cnts[2], MAXL2);
    for (int i = t; i < MAXS1 * 64; i += 256) s_acc[i] = 0.f;
    if (t < 192) s_agg2[t] = 0.f;
    if (t < ns1) s_s2i[t] = slot2[S1[t]];
    __syncthreads();

    // ---- agg1 over L2 edges + S1 self-loops: resolve (thread-parallel) then
    //      accumulate (wave-per-edge, 8 gathers in flight)
    int ntot = nl2 + ns1;
    for (int e0 = 0; e0 < ntot; e0 += CHUNK) {
        int cn = min(CHUNK, ntot - e0);
        if (t < cn) {
            int e = e0 + t;
            int r, c;
            if (e < nl2) { int2 rc = L2[e]; r = rc.x; c = rc.y; }
            else { r = c = S1[e - nl2]; }
            int sr2 = slot2[r], sc2 = slot2[c], sc1 = slot1[c];
            int a = -1, bb = -1; float w = 0.f;
            if ((unsigned)sr2 < MAXS2 && (unsigned)sc2 < MAXS2 && (unsigned)sc1 < (unsigned)ns1) {
                w = rsqrtf((float)(degc[sr2] + 1)) * rsqrtf((float)(degc[sc2] + 1));
                a = sr2; bb = sc1;
            }
            e_a[t] = a; e_b[t] = bb; e_w[t] = w;
        }
        __syncthreads();
        for (int base = wid * 8; base < cn; base += 32) {
            float v[8]; int bb[8];
#pragma unroll
            for (int u = 0; u < 8; u++) {
                int e = base + u;
                int a  = (e < cn) ? e_a[e] : -1;
                bb[u]  = (e < cn && a >= 0) ? e_b[e] : -1;
                v[u]   = (a >= 0) ? h1c[a * 64 + lane] * e_w[e] : 0.f;
            }
#pragma unroll
            for (int u = 0; u < 8; u++)
                if (bb[u] >= 0) atomicAdd(&s_acc[bb[u] * 64 + lane], v[u]);
        }
        __syncthreads();
    }

    // ---- x1 = LN(x0 + agg1 + g1b); h2 = x1 @ g2w
    for (int s = wid; s < ns1; s += 4) {
        int s2 = s_s2i[s];
        float v = x0c[s2 * 64 + lane] + s_acc[s * 64 + lane] + g1b[lane];
        float sum = wave_sum64(v), sq = wave_sum64(v * v);
        float mean = sum * (1.f / 64.f);
        float var = sq * (1.f / 64.f) - mean * mean;
        float x1 = (v - mean) * rsqrtf(var + 1e-5f) * ln1w[lane] + ln1b[lane];
        s_acc[s * 64 + lane] = x1;
        float h = 0.f;
#pragma unroll
        for (int j = 0; j < 64; j++) {
            float xj = __shfl(x1, j, 64);
            h = fmaf(xj, g2w[j * 64 + lane], h);
        }
        s_h2[s * 64 + lane] = h;
    }
    __syncthreads();

    // ---- agg2 over L1 edges + {0,1,2} self-loops: resolve then accumulate (LDS src)
    int ntot2 = nl1 + 3;
    for (int e0 = 0; e0 < ntot2; e0 += CHUNK) {
        int cn = min(CHUNK, ntot2 - e0);
        if (t < cn) {
            int e = e0 + t;
            int r, c;
            if (e < nl1) { int2 rc = L1[e]; r = rc.x; c = rc.y; }
            else { r = c = e - nl1; }
            int sr1 = slot1[r], sr2 = slot2[r], sc2 = slot2[c];
            int a = -1, bb = -1; float w = 0.f;
            if ((unsigned)sr1 < (unsigned)ns1 && (unsigned)sr2 < MAXS2 && (unsigned)sc2 < MAXS2) {
                w = rsqrtf((float)(degc[sr2] + 1)) * rsqrtf((float)(degc[sc2] + 1));
                a = sr1; bb = c;
            }
            e_a[t] = a; e_b[t] = bb; e_w[t] = w;
        }
        __syncthreads();
        for (int e = wid; e < cn; e += 4) {
            int a = e_a[e];
            if (a < 0) continue;
            atomicAdd(&s_agg2[e_b[e] * 64 + lane], s_h2[a * 64 + lane] * e_w[e]);
        }
        __syncthreads();
    }

    // ---- x2 = LN(x1 + agg2 + g2b), nodes 0..2
    if (wid < 3) {
        int s1 = slot1[wid];
        float v = s_acc[s1 * 64 + lane] + s_agg2[wid * 64 + lane] + g2b[lane];
        float sum = wave_sum64(v), sq = wave_sum64(v * v);
        float mean = sum * (1.f / 64.f);
        float var = sq * (1.f / 64.f) - mean * mean;
        s_x2[wid * 64 + lane] = (v - mean) * rsqrtf(var + 1e-5f) * ln2w[lane] + ln2b[lane];
    }
    __syncthreads();

    // ---- hg = relu(x2 @ gw1 + gb1)
    const float* W1[3] = {w10, w11, w12};
    const float* B1[3] = {b10, b11, b12};
#pragma unroll
    for (int gi = 0; gi < 3; gi++) {
        float acc = B1[gi][t];
#pragma unroll
        for (int j = 0; j < 64; j++) acc = fmaf(s_x2[gi * 64 + j], W1[gi][j * 256 + t], acc);
        hg[gi * 256 + t] = fmaxf(acc, 0.f);
    }
}

// ---- 6: out GEMV, split-K: 4 waves x 64 cols per block
__global__ __launch_bounds__(256) void k_out(const float* __restrict__ hg,
        const float* __restrict__ w20, const float* __restrict__ b20,
        const float* __restrict__ w21, const float* __restrict__ b21,
        const float* __restrict__ w22, const float* __restrict__ b22,
        float* __restrict__ out) {
    __shared__ float lh[768];
    __shared__ float part[256];
    int t = threadIdx.x;
    lh[t] = hg[t]; lh[t + 256] = hg[t + 256]; lh[t + 512] = hg[t + 512];
    __syncthreads();
    int tx = t & 63, ty = t >> 6;
    int o = blockIdx.x * 64 + tx;
    int gi = -1, jj = 0, od = 1;
    const float* w2 = w20;
    if (o < OD0)                 { gi = 0; jj = o;             od = OD0; w2 = w20; }
    else if (o < OD0 + OD1)      { gi = 1; jj = o - OD0;       od = OD1; w2 = w21; }
    else if (o < OUT_TOTAL)      { gi = 2; jj = o - OD0 - OD1; od = OD2; w2 = w22; }
    float acc = 0.f;
    if (gi >= 0) {
        const float* h = &lh[gi * 256 + ty * 64];
        const float* wp = &w2[(size_t)(ty * 64) * od + jj];
#pragma unroll 16
        for (int k = 0; k < 64; k++) acc = fmaf(h[k], wp[(size_t)k * od], acc);
    }
    part[t] = acc;
    __syncthreads();
    if (t < 64 && gi >= 0) {
        float r = part[t] + part[t + 64] + part[t + 128] + part[t + 192];
        const float* b2 = (gi == 0) ? b20 : (gi == 1) ? b21 : b22;
        out[o] = r + b2[jj];
    }
}

extern "C" void kernel_launch(void* const* d_in, const int* in_sizes, int n_in,
                              void* d_out, int out_size, void* d_ws, size_t ws_size,
                              hipStream_t stream) {
    (void)in_sizes; (void)n_in; (void)out_size; (void)ws_size;
    const float* latent = (const float*)d_in[0];
    const int*   edges  = (const int*)d_in[1];
    const float* wq  = (const float*)d_in[2];
    const float* bq  = (const float*)d_in[3];
    const float* wk  = (const float*)d_in[4];
    const float* bk  = (const float*)d_in[5];
    const float* wv  = (const float*)d_in[6];
    const float* bv  = (const float*)d_in[7];
    const float* ln0w = (const float*)d_in[8];
    const float* ln0b = (const float*)d_in[9];
    const float* g1w  = (const float*)d_in[10];
    const float* g1b  = (const float*)d_in[11];
    const float* ln1w = (const float*)d_in[12];
    const float* ln1b = (const float*)d_in[13];
    const float* g2w  = (const float*)d_in[14];
    const float* g2b  = (const float*)d_in[15];
    const float* ln2w = (const float*)d_in[16];
    const float* ln2b = (const float*)d_in[17];
    const float* gw1_0 = (const float*)d_in[18];
    const float* gb1_0 = (const float*)d_in[19];
    const float* gw2_0 = (const float*)d_in[20];
    const float* gb2_0 = (const float*)d_in[21];
    const float* gw1_1 = (const float*)d_in[22];
    const float* gb1_1 = (const float*)d_in[23];
    const float* gw2_1 = (const float*)d_in[24];
    const float* gb2_1 = (const float*)d_in[25];
    const float* gw1_2 = (const float*)d_in[26];
    const float* gb1_2 = (const float*)d_in[27];
    const float* gw2_2 = (const float*)d_in[28];
    const float* gb2_2 = (const float*)d_in[29];

    // workspace carve: [cnts|mask1|mask2|degc] contiguous -> zeroed by k_init
    char* ptr = (char*)d_ws;
    auto alloc = [&](size_t bytes) { char* r = ptr; ptr += (bytes + 255) & ~(size_t)255; return r; };
    int*      cnts  = (int*)alloc(64 * 4);        // [0]=nL1 [1]=nS1 [2]=nL2 [3]=nS2
    unsigned* mask1 = (unsigned*)alloc(MASKW * 4);
    unsigned* mask2 = (unsigned*)alloc(MASKW * 4);
    int*      degc  = (int*)alloc((size_t)MAXS2 * 4);
    char*     zero_end = ptr;
    int*      slot1 = (int*)alloc((size_t)NN * 4);   // valid only where mask1 bit set
    int*      slot2 = (int*)alloc((size_t)NN * 4);   // valid only where mask2 bit set
    int2*     L1    = (int2*)alloc((size_t)MAXL1 * 8);
    int*      S1    = (int*)alloc((size_t)MAXS1 * 4);
    int2*     L2    = (int2*)alloc((size_t)MAXL2 * 8);
    int*      S2    = (int*)alloc((size_t)MAXS2 * 4);
    float*    x0c   = (float*)alloc((size_t)MAXS2 * 64 * 4);
    float*    h1c   = (float*)alloc((size_t)MAXS2 * 64 * 4);
    float*    hg    = (float*)alloc(3 * HIDN * 4);

    const int* erow = edges;
    const int* ecol = edges + NE;
    int zero_n4 = (int)((zero_end - (char*)cnts) / 16);

    const int SCAN_GRID = (NE / 4 + 255) / 256;
    k_init<<<16, 256, 0, stream>>>((int4*)cnts, zero_n4);
    k_scan1<<<SCAN_GRID, 256, 0, stream>>>(erow, ecol, cnts, mask1, slot1, S1, L1);
    k_scan2<<<SCAN_GRID, 256, 0, stream>>>(erow, ecol, cnts, mask1, mask2, slot2, S2, S1, L2);
    k_degx0<<<DX_GRID, 256, 0, stream>>>(cnts, ecol, mask2, slot2, degc, S2, latent,
                                         wq, bq, wk, bk, wv, bv, ln0w, ln0b, g1w, x0c, h1c);
    k_tail<<<1, 256, 0, stream>>>(cnts, L1, L2, S1, slot1, slot2, degc, x0c, h1c,
                                  g1b, ln1w, ln1b, g2w, g2b, ln2w, ln2b,
                                  gw1_0, gb1_0, gw1_1, gb1_1, gw1_2, gb1_2, hg);
    k_out<<<(OUT_TOTAL + 63) / 64, 256, 0, stream>>>(hg, gw2_0, gb2_0, gw2_1, gb2_1,
                                                     gw2_2, gb2_2, (float*)d_out);
}